// Round 1
// baseline (3997.194 us; speedup 1.0000x reference)
//
#include <hip/hip_runtime.h>
#include <hip/hip_bf16.h>

#define T_  4
#define C_  256
#define H_  256
#define W_  256
#define S_  9
#define HW_ (H_*W_)
#define NH  4
#define HD  64
#define KK  25

// ---------------------------------------------------------------------------
// GEMM: O[t][co][hw] = scale * sum_ci A[t][ci][hw] * B[ci][co]
// A channel-major [T,C,HW], B row-major [C,C], O channel-major [T,C,HW].
// Tile 128(n) x 128(co), BK=16, 256 threads, 8x8 microtile per thread.
// gridDim.z selects (B, O) pair; z==0 applies `scale0`.
// ---------------------------------------------------------------------------
__global__ __launch_bounds__(256)
void gemm3(const float* __restrict__ A,
           const float* __restrict__ B0, const float* __restrict__ B1,
           const float* __restrict__ B2,
           float* __restrict__ O0, float* __restrict__ O1, float* __restrict__ O2,
           float scale0)
{
    const int z = blockIdx.z;
    const float* __restrict__ B = (z == 0) ? B0 : ((z == 1) ? B1 : B2);
    float* __restrict__ O       = (z == 0) ? O0 : ((z == 1) ? O1 : O2);
    const float scale = (z == 0) ? scale0 : 1.0f;

    const int n0  = blockIdx.x * 128;       // global n = t*HW + hw
    const int t   = n0 >> 16;               // HW = 65536
    const int hw0 = n0 & (HW_ - 1);
    const int co0 = blockIdx.y * 128;

    __shared__ float As[16][128];
    __shared__ float Bs[16][128];

    const int tid = threadIdx.x;
    const int tx  = tid & 15;    // n subtile
    const int ty  = tid >> 4;    // co subtile

    float acc[8][8];
#pragma unroll
    for (int i = 0; i < 8; i++)
#pragma unroll
        for (int j = 0; j < 8; j++) acc[i][j] = 0.0f;

    const float* Abase = A + (size_t)t * C_ * HW_ + hw0;

    for (int k0 = 0; k0 < C_; k0 += 16) {
        // stage A and B tiles (float4, coalesced)
#pragma unroll
        for (int i = 0; i < 2; i++) {
            int e  = tid + 256 * i;          // 0..511
            int ci = e >> 5;                 // 0..15
            int n4 = e & 31;                 // 0..31 (float4 index)
            float4 av = *(const float4*)(Abase + (size_t)(k0 + ci) * HW_ + n4 * 4);
            *(float4*)&As[ci][n4 * 4] = av;
            float4 bv = *(const float4*)(B + (size_t)(k0 + ci) * C_ + co0 + n4 * 4);
            *(float4*)&Bs[ci][n4 * 4] = bv;
        }
        __syncthreads();

#pragma unroll
        for (int ci = 0; ci < 16; ci++) {
            float4 a0 = *(float4*)&As[ci][tx * 8];
            float4 a1 = *(float4*)&As[ci][tx * 8 + 4];
            float4 b0 = *(float4*)&Bs[ci][ty * 8];
            float4 b1 = *(float4*)&Bs[ci][ty * 8 + 4];
            float a[8] = {a0.x, a0.y, a0.z, a0.w, a1.x, a1.y, a1.z, a1.w};
            float b[8] = {b0.x, b0.y, b0.z, b0.w, b1.x, b1.y, b1.z, b1.w};
#pragma unroll
            for (int i = 0; i < 8; i++)
#pragma unroll
                for (int j = 0; j < 8; j++) acc[i][j] += a[i] * b[j];
        }
        __syncthreads();
    }

    // store: for each of 8 co rows, two float4 along n
    float* Obase = O + (size_t)t * C_ * HW_ + hw0 + tx * 8;
#pragma unroll
    for (int j = 0; j < 8; j++) {
        float* row = Obase + (size_t)(co0 + ty * 8 + j) * HW_;
        float4 v0 = make_float4(acc[0][j] * scale, acc[1][j] * scale,
                                acc[2][j] * scale, acc[3][j] * scale);
        float4 v1 = make_float4(acc[4][j] * scale, acc[5][j] * scale,
                                acc[6][j] * scale, acc[7][j] * scale);
        *(float4*)(row)     = v0;
        *(float4*)(row + 4) = v1;
    }
}

// ---------------------------------------------------------------------------
// Attention: block = 64-pixel strip at (t, h, w0..w0+63), 256 threads.
// wave (tid>>6) = head, lane (tid&63) = pixel.
// q,k,v channel-major [T,C,HW]; sims [T,S,H,W]; out channel-major [T,C,HW].
// ---------------------------------------------------------------------------
__global__ __launch_bounds__(256)
void attn_kernel(const float* __restrict__ q, const float* __restrict__ k,
                 const float* __restrict__ v, const float* __restrict__ sims,
                 float* __restrict__ aout)
{
    const int w0   = blockIdx.x * 64;
    const int h    = blockIdx.y;
    const int t    = blockIdx.z;
    const int tid  = threadIdx.x;
    const int lane = tid & 63;
    const int wave = tid >> 6;
    const int w    = w0 + lane;
    const int hw   = h * W_ + w;

    __shared__ float lw[NH][KK][64];   // logits -> weights
    __shared__ float sw[KK][64];       // superpixel sim weights

    // per-lane neighbor flat offsets (static-indexed register array)
    int off[KK];
#pragma unroll
    for (int kk = 0; kk < KK; kk++) {
        int di = kk / 5 - 2, dj = kk % 5 - 2;
        int h2 = min(max(h + di, 0), H_ - 1);
        int w2 = min(max(w + dj, 0), W_ - 1);
        off[kk] = h2 * W_ + w2;
    }

    const size_t tbase = (size_t)t * C_ * HW_;

    // --- superpixel similarity weights (distributed over waves) ---
    {
        const float* simsT = sims + (size_t)t * S_ * HW_;
        for (int kk = wave; kk < KK; kk += 4) {
            int di = kk / 5 - 2, dj = kk % 5 - 2;
            int h2 = min(max(h + di, 0), H_ - 1);
            int w2 = min(max(w + dj, 0), W_ - 1);
            int o  = h2 * W_ + w2;
            float acc = 0.0f;
#pragma unroll
            for (int s = 0; s < S_; s++)
                acc += simsT[s * HW_ + hw] * simsT[s * HW_ + o];
            sw[kk][lane] = acc;
        }
    }

    // --- QK logits: wave handles its head, q row cached in registers ---
    {
        const int head = wave;
        const float* qh = q + tbase + (size_t)(head * HD) * HW_;
        const float* kh = k + tbase + (size_t)(head * HD) * HW_;
        float qr[HD];
#pragma unroll
        for (int c = 0; c < HD; c++) qr[c] = qh[(size_t)c * HW_ + hw];
#pragma unroll 1
        for (int kk = 0; kk < KK; kk++) {
            int di = kk / 5 - 2, dj = kk % 5 - 2;
            int h2 = min(max(h + di, 0), H_ - 1);
            int w2 = min(max(w + dj, 0), W_ - 1);
            int o  = h2 * W_ + w2;
            float acc = 0.0f;
#pragma unroll
            for (int c = 0; c < HD; c++) acc += qr[c] * kh[(size_t)c * HW_ + o];
            lw[head][kk][lane] = acc;
        }
    }
    __syncthreads();

    // --- softmax-shift, reweight by sim, renormalize (per pixel, per head) ---
    {
        const int head = wave;
        float l[KK];
        float m = -1e30f;
#pragma unroll
        for (int kk = 0; kk < KK; kk++) { l[kk] = lw[head][kk][lane]; m = fmaxf(m, l[kk]); }
        float ssum = 0.0f;
#pragma unroll
        for (int kk = 0; kk < KK; kk++) { l[kk] = __expf(l[kk] - m) * sw[kk][lane]; ssum += l[kk]; }
        float inv = 1.0f / (1e-10f + ssum);
#pragma unroll
        for (int kk = 0; kk < KK; kk++) lw[head][kk][lane] = l[kk] * inv;
    }
    __syncthreads();

    // --- PV aggregation ---
    {
        const int head = wave;
        float wr[KK];
#pragma unroll
        for (int kk = 0; kk < KK; kk++) wr[kk] = lw[head][kk][lane];
        const float* vh = v + tbase + (size_t)(head * HD) * HW_;
        float*       oh = aout + tbase + (size_t)(head * HD) * HW_;
#pragma unroll 1
        for (int c = 0; c < HD; c++) {
            float acc = 0.0f;
#pragma unroll
            for (int kk = 0; kk < KK; kk++) acc += wr[kk] * vh[(size_t)c * HW_ + off[kk]];
            oh[(size_t)c * HW_ + hw] = acc;
        }
    }
}

// ---------------------------------------------------------------------------
extern "C" void kernel_launch(void* const* d_in, const int* in_sizes, int n_in,
                              void* d_out, int out_size, void* d_ws, size_t ws_size,
                              hipStream_t stream)
{
    const float* x    = (const float*)d_in[0];
    const float* sims = (const float*)d_in[1];
    // d_in[2] = flows: all zeros (wt = 0) -> unused
    const float* Wq   = (const float*)d_in[3];
    const float* Wk   = (const float*)d_in[4];
    const float* Wv   = (const float*)d_in[5];
    const float* Wp   = (const float*)d_in[6];
    float* out = (float*)d_out;

    const size_t NCHW = (size_t)T_ * C_ * HW_;   // 67,108,864 elements
    float* q  = (float*)d_ws;
    float* kk = q  + NCHW;
    float* v  = kk + NCHW;
    float* ao = v  + NCHW;

    // QKV projections (q scaled by hd^-0.5 = 0.125)
    dim3 g1(2048, 2, 3);
    gemm3<<<g1, 256, 0, stream>>>(x, Wq, Wk, Wv, q, kk, v, 0.125f);

    // local-window attention with superpixel reweighting
    dim3 g2(W_ / 64, H_, T_);
    attn_kernel<<<g2, 256, 0, stream>>>(q, kk, v, sims, ao);

    // output projection -> d_out (channel-major == [T,C,H,W])
    dim3 g3(2048, 2, 1);
    gemm3<<<g3, 256, 0, stream>>>(ao, Wp, Wp, Wp, out, out, out, 1.0f);
}

// Round 2
// 1549.881 us; speedup vs baseline: 2.5790x; 2.5790x over previous
//
#include <hip/hip_runtime.h>

#define T_  4
#define C_  256
#define H_  256
#define W_  256
#define S_  9
#define HW_ (H_*W_)
#define NH  4
#define HD  64
#define KK  25

typedef unsigned short ushort_t;
typedef __bf16 bf16x8 __attribute__((ext_vector_type(8)));
typedef float  f32x4  __attribute__((ext_vector_type(4)));

__device__ __forceinline__ unsigned short f2bf(float f) {
    unsigned u = __builtin_bit_cast(unsigned, f);
    u += 0x7fffu + ((u >> 16) & 1u);          // RNE
    return (unsigned short)(u >> 16);
}
__device__ __forceinline__ float bflo(unsigned u) {
    return __builtin_bit_cast(float, u << 16);
}
__device__ __forceinline__ float bfhi(unsigned u) {
    return __builtin_bit_cast(float, u & 0xffff0000u);
}
__device__ __forceinline__ void gload16(const ushort_t* g, ushort_t* l) {
    __builtin_amdgcn_global_load_lds(
        (const __attribute__((address_space(1))) void*)g,
        (__attribute__((address_space(3))) void*)l, 16, 0, 0);
}

// ---------------------------------------------------------------------------
// Weight prep: Wt[1024][256] bf16; rows 0..255 = Wq^T * 0.125, 256.. = Wk^T,
// 512.. = Wv^T, 768.. = Wp^T.   Wt[r][ci] = W[ci][co], co = r & 255.
// ---------------------------------------------------------------------------
__global__ __launch_bounds__(256)
void prep_w(const float* __restrict__ Wq, const float* __restrict__ Wk,
            const float* __restrict__ Wv, const float* __restrict__ Wp,
            ushort_t* __restrict__ Wt)
{
    int r = blockIdx.x;            // 0..1023
    int m = r >> 8, co = r & 255;
    int ci = threadIdx.x;
    const float* W = (m == 0) ? Wq : ((m == 1) ? Wk : ((m == 2) ? Wv : Wp));
    float s = (m == 0) ? 0.125f : 1.0f;
    Wt[(size_t)r * 256 + ci] = f2bf(W[(size_t)ci * 256 + co] * s);
}

// ---------------------------------------------------------------------------
// X cast+transpose: [T,C,HW] fp32 -> [T,HW,C] bf16.  64x64 LDS tiles.
// ---------------------------------------------------------------------------
__global__ __launch_bounds__(256)
void cast_x(const float* __restrict__ X, ushort_t* __restrict__ Xt)
{
    int hw0 = blockIdx.x * 64, c0 = blockIdx.y * 64, t = blockIdx.z;
    __shared__ ushort_t lds[64][68];
    int tid = threadIdx.x;
    const float* xb = X + ((size_t)t * C_ + c0) * HW_ + hw0;
#pragma unroll
    for (int i = 0; i < 4; i++) {
        int idx = tid + i * 256;
        int c = idx >> 4, col4 = idx & 15;
        float4 v = *(const float4*)(xb + (size_t)c * HW_ + col4 * 4);
        ushort4 u = make_ushort4(f2bf(v.x), f2bf(v.y), f2bf(v.z), f2bf(v.w));
        *(ushort4*)&lds[c][col4 * 4] = u;
    }
    __syncthreads();
    ushort_t* ob = Xt + ((size_t)t * HW_ + hw0) * C_ + c0;
#pragma unroll
    for (int i = 0; i < 4; i++) {
        int idx = tid + i * 256;
        int hw = idx >> 4, c4 = idx & 15;
        ushort4 u = make_ushort4(lds[c4 * 4 + 0][hw], lds[c4 * 4 + 1][hw],
                                 lds[c4 * 4 + 2][hw], lds[c4 * 4 + 3][hw]);
        *(ushort4*)(ob + (size_t)hw * C_ + c4 * 4) = u;
    }
}

// ---------------------------------------------------------------------------
// MFMA GEMM: C[n][co] = sum_ci A[n][ci] * Bt[co][ci], A pixel-major bf16,
// Bt = pre-transposed weights bf16.  Tile 128x128, BK=32, 4 waves @ 64x64.
// mode 0: bf16 out, split by co into o0/o1/o2 (pixel-major [n][256]).
// mode 1: fp32 out channel-major [T,C,H,W] (float4 along n).
// ---------------------------------------------------------------------------
__global__ __launch_bounds__(256)
void gemm_mfma(const ushort_t* __restrict__ A, const ushort_t* __restrict__ Bt,
               ushort_t* __restrict__ o0, ushort_t* __restrict__ o1,
               ushort_t* __restrict__ o2, float* __restrict__ of, int mode)
{
    __shared__ ushort_t As[128 * 32];
    __shared__ ushort_t Bs[128 * 32];
    const int tid = threadIdx.x, ln = tid & 63, wv = tid >> 6;
    const int n0  = blockIdx.x * 128;
    const int co0 = blockIdx.y * 128;
    const int m_off = (wv & 1) * 64, n_off = (wv >> 1) * 64;

    f32x4 acc[4][4];
#pragma unroll
    for (int i = 0; i < 4; i++)
#pragma unroll
        for (int j = 0; j < 4; j++) acc[i][j] = (f32x4){0.f, 0.f, 0.f, 0.f};

    const int srow = ln >> 2, scol = (ln & 3) * 8;
    const ushort_t* gA = A  + (size_t)(n0  + srow) * 256 + scol;
    const ushort_t* gB = Bt + (size_t)(co0 + srow) * 256 + scol;
    const int quad = ln >> 4, lm = ln & 15;

#pragma unroll
    for (int k0 = 0; k0 < 256; k0 += 32) {
#pragma unroll
        for (int c = 0; c < 2; c++) {
            int rr = wv * 32 + c * 16;
            gload16(gA + (size_t)rr * 256 + k0, As + rr * 32);
            gload16(gB + (size_t)rr * 256 + k0, Bs + rr * 32);
        }
        __syncthreads();
        bf16x8 af[4], bfr[4];
#pragma unroll
        for (int mt = 0; mt < 4; mt++)
            af[mt] = *(const bf16x8*)&As[(m_off + mt * 16 + lm) * 32 + quad * 8];
#pragma unroll
        for (int nt = 0; nt < 4; nt++)
            bfr[nt] = *(const bf16x8*)&Bs[(n_off + nt * 16 + lm) * 32 + quad * 8];
#pragma unroll
        for (int mt = 0; mt < 4; mt++)
#pragma unroll
            for (int nt = 0; nt < 4; nt++)
                acc[mt][nt] = __builtin_amdgcn_mfma_f32_16x16x32_bf16(
                    af[mt], bfr[nt], acc[mt][nt], 0, 0, 0);
        __syncthreads();
    }

    if (mode == 0) {
        int arr = co0 >> 8;
        ushort_t* op = (arr == 0) ? o0 : ((arr == 1) ? o1 : o2);
        int cobase = (co0 & 255) + n_off;
#pragma unroll
        for (int mt = 0; mt < 4; mt++) {
            int nb = n0 + m_off + mt * 16 + quad * 4;
#pragma unroll
            for (int nt = 0; nt < 4; nt++) {
                int ci = cobase + nt * 16 + lm;
#pragma unroll
                for (int r = 0; r < 4; r++)
                    op[(size_t)(nb + r) * 256 + ci] = f2bf(acc[mt][nt][r]);
            }
        }
    } else {
#pragma unroll
        for (int mt = 0; mt < 4; mt++) {
            int nb = n0 + m_off + mt * 16 + quad * 4;
            int tt = nb >> 16, hwb = nb & (HW_ - 1);
            float* ob = of + (size_t)tt * (C_ * (size_t)HW_) + hwb;
#pragma unroll
            for (int nt = 0; nt < 4; nt++) {
                int cg = co0 + n_off + nt * 16 + lm;
                float4 val = make_float4(acc[mt][nt][0], acc[mt][nt][1],
                                         acc[mt][nt][2], acc[mt][nt][3]);
                *(float4*)(ob + (size_t)cg * HW_) = val;
            }
        }
    }
}

// ---------------------------------------------------------------------------
// Attention: pixel-major bf16 q/k/v [T*HW][256]. Block = 64-pixel strip,
// wave = head, lane = pixel. Logits + sim weights via LDS (dynamic indexing).
// ---------------------------------------------------------------------------
__global__ __launch_bounds__(256)
void attn2(const ushort_t* __restrict__ q, const ushort_t* __restrict__ k,
           const ushort_t* __restrict__ v, const float* __restrict__ sims,
           ushort_t* __restrict__ ao)
{
    const int w0 = blockIdx.x * 64, h = blockIdx.y, t = blockIdx.z;
    const int tid = threadIdx.x, ln = tid & 63, head = tid >> 6;
    const int w = w0 + ln, hw = h * W_ + w;
    const size_t npix = (size_t)t * HW_ + hw;

    __shared__ float lw[NH][KK][64];
    __shared__ float sw[KK][64];

    // superpixel similarity weights, split across waves
    {
        const float* sp = sims + (size_t)t * S_ * HW_;
        float s0[S_];
#pragma unroll
        for (int s = 0; s < S_; s++) s0[s] = sp[s * HW_ + hw];
#pragma unroll 1
        for (int e = head; e < KK; e += NH) {
            int di = e / 5 - 2, dj = e % 5 - 2;
            int h2 = min(max(h + di, 0), H_ - 1);
            int w2 = min(max(w + dj, 0), W_ - 1);
            int o = h2 * W_ + w2;
            float a = 0.f;
#pragma unroll
            for (int s = 0; s < S_; s++) a += s0[s] * sp[s * HW_ + o];
            sw[e][ln] = a;
        }
    }

    // q into registers (fp32)
    const ushort_t* qb = q + npix * 256 + head * HD;
    float qf[HD];
#pragma unroll
    for (int i = 0; i < 8; i++) {
        uint4 x = *(const uint4*)(qb + i * 8);
        qf[i*8+0] = bflo(x.x); qf[i*8+1] = bfhi(x.x);
        qf[i*8+2] = bflo(x.y); qf[i*8+3] = bfhi(x.y);
        qf[i*8+4] = bflo(x.z); qf[i*8+5] = bfhi(x.z);
        qf[i*8+6] = bflo(x.w); qf[i*8+7] = bfhi(x.w);
    }

    const size_t tbase = (size_t)t * HW_ * 256;
    const ushort_t* kb = k + tbase + head * HD;

    // QK logits -> LDS
#pragma unroll 1
    for (int e = 0; e < KK; e++) {
        int di = e / 5 - 2, dj = e % 5 - 2;
        int h2 = min(max(h + di, 0), H_ - 1);
        int w2 = min(max(w + dj, 0), W_ - 1);
        int o = h2 * W_ + w2;
        const ushort_t* kp = kb + (size_t)o * 256;
        float a = 0.f;
#pragma unroll
        for (int i = 0; i < 8; i++) {
            uint4 kv = *(const uint4*)(kp + i * 8);
            a += qf[i*8+0] * bflo(kv.x); a += qf[i*8+1] * bfhi(kv.x);
            a += qf[i*8+2] * bflo(kv.y); a += qf[i*8+3] * bfhi(kv.y);
            a += qf[i*8+4] * bflo(kv.z); a += qf[i*8+5] * bfhi(kv.z);
            a += qf[i*8+6] * bflo(kv.w); a += qf[i*8+7] * bfhi(kv.w);
        }
        lw[head][e][ln] = a;
    }
    __syncthreads();   // sw ready (lw is own-wave)

    // exp-shift, reweight by sim, normalize
    float mx = -1e30f;
#pragma unroll 1
    for (int e = 0; e < KK; e++) mx = fmaxf(mx, lw[head][e][ln]);
    float sum = 0.f;
#pragma unroll 1
    for (int e = 0; e < KK; e++) {
        float p = __expf(lw[head][e][ln] - mx) * sw[e][ln];
        sum += p;
        lw[head][e][ln] = p;
    }
    const float inv = 1.0f / (1e-10f + sum);

    // PV, 32 channels at a time
    const ushort_t* vb = v + tbase + head * HD;
    ushort_t* ab = ao + npix * 256 + head * HD;
#pragma unroll 1
    for (int half = 0; half < 2; half++) {
        float oa[32];
#pragma unroll
        for (int i = 0; i < 32; i++) oa[i] = 0.f;
#pragma unroll 1
        for (int e = 0; e < KK; e++) {
            int di = e / 5 - 2, dj = e % 5 - 2;
            int h2 = min(max(h + di, 0), H_ - 1);
            int w2 = min(max(w + dj, 0), W_ - 1);
            int o = h2 * W_ + w2;
            float wgt = lw[head][e][ln] * inv;
            const ushort_t* vp = vb + (size_t)o * 256 + half * 32;
#pragma unroll
            for (int i = 0; i < 4; i++) {
                uint4 vv = *(const uint4*)(vp + i * 8);
                oa[i*8+0] += wgt * bflo(vv.x); oa[i*8+1] += wgt * bfhi(vv.x);
                oa[i*8+2] += wgt * bflo(vv.y); oa[i*8+3] += wgt * bfhi(vv.y);
                oa[i*8+4] += wgt * bflo(vv.z); oa[i*8+5] += wgt * bfhi(vv.z);
                oa[i*8+6] += wgt * bflo(vv.w); oa[i*8+7] += wgt * bfhi(vv.w);
            }
        }
        unsigned pk[16];
#pragma unroll
        for (int j = 0; j < 16; j++)
            pk[j] = (unsigned)f2bf(oa[2*j]) | ((unsigned)f2bf(oa[2*j+1]) << 16);
        uint4* stp = (uint4*)(ab + half * 32);
#pragma unroll
        for (int i = 0; i < 4; i++)
            stp[i] = make_uint4(pk[i*4+0], pk[i*4+1], pk[i*4+2], pk[i*4+3]);
    }
}

// ---------------------------------------------------------------------------
extern "C" void kernel_launch(void* const* d_in, const int* in_sizes, int n_in,
                              void* d_out, int out_size, void* d_ws, size_t ws_size,
                              hipStream_t stream)
{
    const float* x    = (const float*)d_in[0];
    const float* sims = (const float*)d_in[1];
    // d_in[2] = flows: zeros (wt = 0) -> unused
    const float* Wq   = (const float*)d_in[3];
    const float* Wk   = (const float*)d_in[4];
    const float* Wv   = (const float*)d_in[5];
    const float* Wp   = (const float*)d_in[6];
    float* out = (float*)d_out;

    const size_t NPIX = (size_t)T_ * HW_;        // 262144
    const size_t NCH  = NPIX * 256;              // elements per tensor

    ushort_t* Wt = (ushort_t*)d_ws;                       // 512 KB
    ushort_t* Xt = (ushort_t*)((char*)d_ws + (1 << 20));  // 134 MB each below
    ushort_t* qq = Xt + NCH;
    ushort_t* kk = qq + NCH;
    ushort_t* vv = kk + NCH;
    ushort_t* ao = vv + NCH;

    prep_w<<<1024, 256, 0, stream>>>(Wq, Wk, Wv, Wp, Wt);
    cast_x<<<dim3(HW_ / 64, C_ / 64, T_), 256, 0, stream>>>(x, Xt);

    // QKV: N = 768 (q|k|v stacked in Wt rows 0..767)
    gemm_mfma<<<dim3(NPIX / 128, 6), 256, 0, stream>>>(Xt, Wt, qq, kk, vv, nullptr, 0);

    attn2<<<dim3(W_ / 64, H_, T_), 256, 0, stream>>>(qq, kk, vv, sims, ao);

    // output projection: Wp^T at rows 768.., fp32 channel-major out
    gemm_mfma<<<dim3(NPIX / 128, 2), 256, 0, stream>>>(ao, Wt + 768 * 256,
                                                       nullptr, nullptr, nullptr, out, 1);
}